// Round 9
// baseline (73.544 us; speedup 1.0000x reference)
//
#include <hip/hip_runtime.h>

// SSIM loss, wave-autonomous vertical-first + FENCED software pipeline.
// x,y f32 [32,3,512,512] -> 2x2 pool (256x256) -> separable 11x11 Gaussian ->
// SSIM map 246x246 -> 1 - mean.
// Wave = (plane, 12-row output strip); 4 pooled cols/lane * 64 lanes = 256 cols.
// R7 post-mortem: compiler re-sank the raw-load consumption to the load site
// (VGPR stayed 112, dur identical to R2). R8 forces the pipeline with
// sched_barrier(0) fences + 2x-unrolled loop with named rawA/rawB buffers:
//   step_row(i) | pool rawA + issue row i+3 | step_row(i+1) | pool rawB + issue i+4
// so every load has a full step_row (~1600 cyc) between issue and vmcnt wait.
// No launch_bounds min-waves (R4 lesson). H=12 is the FETCH-minimal config.

#define KS 11
#define H 12
#define ROWS (H + KS - 1)        // 22 pooled rows per strip
#define NSTRIP 21                // 21*12 = 252 >= 246
#define NPLANE 96
#define NWAVE (NPLANE * NSTRIP)  // 2016
#define NBLOCK (NWAVE / 4)       // 504
#define OUTD 246
#define BUFW 272                 // 256 + 16 pad cols (zeroed)
#define C1V 1e-4f
#define C2V 9e-4f

__device__ __forceinline__ void load_pool(const float* __restrict__ xp,
                                          const float* __restrict__ yp,
                                          int r0, int i, int lane,
                                          float (&px)[4], float (&py)[4]) {
    int pr = r0 + i; pr = pr > 255 ? 255 : pr;
    const float* xr = xp + (size_t)(2 * pr) * 512 + 8 * lane;
    const float* yr = yp + (size_t)(2 * pr) * 512 + 8 * lane;
    float4 a0 = *(const float4*)xr;
    float4 a1 = *(const float4*)(xr + 4);
    float4 b0 = *(const float4*)(xr + 512);
    float4 b1 = *(const float4*)(xr + 516);
    float4 c0 = *(const float4*)yr;
    float4 c1 = *(const float4*)(yr + 4);
    float4 d0 = *(const float4*)(yr + 512);
    float4 d1 = *(const float4*)(yr + 516);
    px[0] = (a0.x + a0.y + b0.x + b0.y) * 0.25f;
    px[1] = (a0.z + a0.w + b0.z + b0.w) * 0.25f;
    px[2] = (a1.x + a1.y + b1.x + b1.y) * 0.25f;
    px[3] = (a1.z + a1.w + b1.z + b1.w) * 0.25f;
    py[0] = (c0.x + c0.y + d0.x + d0.y) * 0.25f;
    py[1] = (c0.z + c0.w + d0.z + d0.w) * 0.25f;
    py[2] = (c1.x + c1.y + d1.x + d1.y) * 0.25f;
    py[3] = (c1.z + c1.w + d1.z + d1.w) * 0.25f;
}

// issue-only: raw 16B loads, no arithmetic on results
__device__ __forceinline__ void issue_row(const float* __restrict__ xp,
                                          const float* __restrict__ yp,
                                          int r0, int i, int lane,
                                          float4 (&rawx)[4], float4 (&rawy)[4]) {
    int pr = r0 + i; pr = pr > 255 ? 255 : pr;
    const float* xr = xp + (size_t)(2 * pr) * 512 + 8 * lane;
    const float* yr = yp + (size_t)(2 * pr) * 512 + 8 * lane;
    rawx[0] = *(const float4*)xr;
    rawx[1] = *(const float4*)(xr + 4);
    rawx[2] = *(const float4*)(xr + 512);
    rawx[3] = *(const float4*)(xr + 516);
    rawy[0] = *(const float4*)yr;
    rawy[1] = *(const float4*)(yr + 4);
    rawy[2] = *(const float4*)(yr + 512);
    rawy[3] = *(const float4*)(yr + 516);
}

__device__ __forceinline__ void pool_raw(const float4 (&rawx)[4], const float4 (&rawy)[4],
                                         float (&px)[4], float (&py)[4]) {
    px[0] = (rawx[0].x + rawx[0].y + rawx[2].x + rawx[2].y) * 0.25f;
    px[1] = (rawx[0].z + rawx[0].w + rawx[2].z + rawx[2].w) * 0.25f;
    px[2] = (rawx[1].x + rawx[1].y + rawx[3].x + rawx[3].y) * 0.25f;
    px[3] = (rawx[1].z + rawx[1].w + rawx[3].z + rawx[3].w) * 0.25f;
    py[0] = (rawy[0].x + rawy[0].y + rawy[2].x + rawy[2].y) * 0.25f;
    py[1] = (rawy[0].z + rawy[0].w + rawy[2].z + rawy[2].w) * 0.25f;
    py[2] = (rawy[1].x + rawy[1].y + rawy[3].x + rawy[3].y) * 0.25f;
    py[3] = (rawy[1].z + rawy[1].w + rawy[3].z + rawy[3].w) * 0.25f;
}

__device__ __forceinline__ void step_row(float* vb, const float (&wt)[KS],
                                         float (&rx)[KS][4], float (&ry)[KS][4],
                                         const float (&px)[4], const float (&py)[4],
                                         int lane, int ro, float& local) {
    // push newest row into slot KS-1
    #pragma unroll
    for (int c = 0; c < 4; ++c) { rx[KS - 1][c] = px[c]; ry[KS - 1][c] = py[c]; }

    // vertical 11-tap, products on the fly (all register, static idx)
    float vmx[4] = {0,0,0,0}, vmy[4] = {0,0,0,0};
    float vxx[4] = {0,0,0,0}, vyy[4] = {0,0,0,0}, vxy[4] = {0,0,0,0};
    #pragma unroll
    for (int k = 0; k < KS; ++k) {
        float wk = wt[k];
        #pragma unroll
        for (int c = 0; c < 4; ++c) {
            float xv = rx[k][c], yv = ry[k][c];
            vmx[c] += wk * xv;       vmy[c] += wk * yv;
            vxx[c] += wk * xv * xv;  vyy[c] += wk * yv * yv;
            vxy[c] += wk * xv * yv;
        }
    }

    // stage 5 V-sum planes to wave-private LDS (b128)
    *(float4*)(vb + 0 * BUFW + 4 * lane) = make_float4(vmx[0], vmx[1], vmx[2], vmx[3]);
    *(float4*)(vb + 1 * BUFW + 4 * lane) = make_float4(vmy[0], vmy[1], vmy[2], vmy[3]);
    *(float4*)(vb + 2 * BUFW + 4 * lane) = make_float4(vxx[0], vxx[1], vxx[2], vxx[3]);
    *(float4*)(vb + 3 * BUFW + 4 * lane) = make_float4(vyy[0], vyy[1], vyy[2], vyy[3]);
    *(float4*)(vb + 4 * BUFW + 4 * lane) = make_float4(vxy[0], vxy[1], vxy[2], vxy[3]);
    __builtin_amdgcn_wave_barrier();   // pin order; in-wave DS ops execute in order

    // horizontal 11-tap: window cols 4l..4l+13 via 4 aligned b128 per plane
    float hp[5][4];
    #pragma unroll
    for (int p = 0; p < 5; ++p) {
        const float* bp = vb + p * BUFW + 4 * lane;
        float4 q0 = *(const float4*)bp;
        float4 q1 = *(const float4*)(bp + 4);
        float4 q2 = *(const float4*)(bp + 8);
        float4 q3 = *(const float4*)(bp + 12);
        float win[16] = {q0.x, q0.y, q0.z, q0.w, q1.x, q1.y, q1.z, q1.w,
                         q2.x, q2.y, q2.z, q2.w, q3.x, q3.y, q3.z, q3.w};
        #pragma unroll
        for (int c = 0; c < 4; ++c) {
            float a = 0.f;
            #pragma unroll
            for (int j = 0; j < KS; ++j) a += wt[j] * win[c + j];
            hp[p][c] = a;
        }
    }

    if (ro < OUTD) {
        #pragma unroll
        for (int c = 0; c < 4; ++c) {
            int oc = 4 * lane + c;
            float mx = hp[0][c], my = hp[1][c];
            float mxx = mx * mx, myy = my * my, mxy = mx * my;
            float sxx = hp[2][c] - mxx, syy = hp[3][c] - myy, sxy = hp[4][c] - mxy;
            float num = (2.f * mxy + C1V) * (2.f * sxy + C2V);
            float den = (mxx + myy + C1V) * (sxx + syy + C2V);
            float ss = num / den;
            local += (oc < OUTD) ? ss : 0.f;
        }
    }

    // rotate ring (static movs)
    #pragma unroll
    for (int k = 0; k < KS - 1; ++k) {
        #pragma unroll
        for (int c = 0; c < 4; ++c) { rx[k][c] = rx[k + 1][c]; ry[k][c] = ry[k + 1][c]; }
    }
}

__global__ __launch_bounds__(256) void ssim_wave(const float* __restrict__ x,
                                                 const float* __restrict__ y,
                                                 double* __restrict__ partial) {
    __shared__ float vbuf[4][5][BUFW];   // wave-private single buffer: 21.25 KB
    const int tid = threadIdx.x;
    const int wv = tid >> 6, lane = tid & 63;
    const int gid = blockIdx.x * 4 + wv;
    const int plane = gid / NSTRIP, strip = gid % NSTRIP;
    const int r0 = strip * H;
    const float* xp = x + (size_t)plane * (512 * 512);
    const float* yp = y + (size_t)plane * (512 * 512);

    float wt[KS];
    {
        float s = 0.f;
        #pragma unroll
        for (int i = 0; i < KS; ++i) {
            float d = (float)i - 5.f;
            wt[i] = expf(-d * d / 4.5f);   // 2*sigma^2 = 4.5
            s += wt[i];
        }
        float inv = 1.f / s;
        #pragma unroll
        for (int i = 0; i < KS; ++i) wt[i] *= inv;
    }

    // zero the 16 pad cols (reads beyond col 255 feed masked outputs)
    if (lane < BUFW - 256) {
        #pragma unroll
        for (int p = 0; p < 5; ++p)
            vbuf[wv][p][256 + lane] = 0.f;
    }
    __builtin_amdgcn_wave_barrier();

    // prime ring: rows 0..9 -> slots 0..9 (independent loads, overlap via TLP)
    float rx[KS][4], ry[KS][4];
    #pragma unroll
    for (int i = 0; i < KS - 1; ++i)
        load_pool(xp, yp, r0, i, lane, rx[i], ry[i]);

    float cpx[4], cpy[4];
    load_pool(xp, yp, r0, KS - 1, lane, cpx, cpy);   // row 10 -> cp

    float local = 0.f;
    float* vb = &vbuf[wv][0][0];

    // pipeline prologue: rows 11,12 in flight
    float4 rAx[4], rAy[4], rBx[4], rBy[4];
    issue_row(xp, yp, r0, KS,     lane, rAx, rAy);   // row 11
    issue_row(xp, yp, r0, KS + 1, lane, rBx, rBy);   // row 12

    #pragma unroll 1
    for (int i = KS - 1; i < ROWS; i += 2) {         // i = 10,12,...,20 (6 iters)
        __builtin_amdgcn_sched_barrier(0);
        step_row(vb, wt, rx, ry, cpx, cpy, lane, r0 + i - (KS - 1), local);
        __builtin_amdgcn_sched_barrier(0);
        pool_raw(rAx, rAy, cpx, cpy);                // vmcnt wait lands here (row i+1)
        issue_row(xp, yp, r0, i + 3, lane, rAx, rAy);
        __builtin_amdgcn_sched_barrier(0);
        step_row(vb, wt, rx, ry, cpx, cpy, lane, r0 + i - (KS - 2), local);
        __builtin_amdgcn_sched_barrier(0);
        pool_raw(rBx, rBy, cpx, cpy);                // row i+2
        issue_row(xp, yp, r0, i + 4, lane, rBx, rBy);
    }

    // wave reduce, one partial per wave
    #pragma unroll
    for (int off = 32; off > 0; off >>= 1)
        local += __shfl_down(local, off, 64);
    if (lane == 0) partial[gid] = (double)local;
}

__global__ __launch_bounds__(256) void ssim_finalize(const double* __restrict__ partial,
                                                     float* __restrict__ out) {
    const int tid = threadIdx.x;
    double s = 0.0;
    for (int i = tid; i < NWAVE; i += 256) s += partial[i];
    #pragma unroll
    for (int off = 32; off > 0; off >>= 1)
        s += __shfl_down(s, off, 64);
    __shared__ double sd[4];
    if ((tid & 63) == 0) sd[tid >> 6] = s;
    __syncthreads();
    if (tid == 0) {
        double total = sd[0] + sd[1] + sd[2] + sd[3];
        const double n = (double)NPLANE * OUTD * OUTD;   // 5,809,536
        out[0] = (float)(1.0 - total / n);
    }
}

extern "C" void kernel_launch(void* const* d_in, const int* in_sizes, int n_in,
                              void* d_out, int out_size, void* d_ws, size_t ws_size,
                              hipStream_t stream) {
    const float* x = (const float*)d_in[0];
    const float* y = (const float*)d_in[1];
    float* out = (float*)d_out;
    double* partial = (double*)d_ws;   // NWAVE * 8 = 15.75 KiB

    ssim_wave<<<NBLOCK, 256, 0, stream>>>(x, y, partial);
    ssim_finalize<<<1, 256, 0, stream>>>(partial, out);
}

// Round 10
// 66.325 us; speedup vs baseline: 1.1088x; 1.1088x over previous
//
#include <hip/hip_runtime.h>

// SSIM loss, wave-autonomous vertical-first + asm-pinned load pipeline.
// x,y f32 [32,3,512,512] -> 2x2 pool (256x256) -> separable 11x11 Gaussian ->
// SSIM map 246x246 -> 1 - mean.
// Wave = (plane, 12-row strip); 4 pooled cols/lane. f32 register ring (11 rows).
// R2/R7/R8 post-mortems: per-step time 5550 cyc vs 1200 VALU -> ~4300 cyc vmcnt
// stall because loads are consumed at issue site; C++ prefetch gets re-folded;
// sched_barrier(0) full-pin regresses. R9: loads via inline-asm
// global_load_dwordx4 (opaque, can't fold), consumed only after an asm
// "s_waitcnt vmcnt(0)" with "+v" pass-through placed AFTER step_row -> the
// wait lands after ~1200 cyc of compute. VGPR ~150-180 (2-wave/SIMD bucket) is
// fine: 504 blocks need only 2 waves/SIMD for full residency.

typedef float f32x4 __attribute__((ext_vector_type(4)));

#define KS 11
#define H 12
#define ROWS (H + KS - 1)        // 22 pooled rows per strip
#define NSTRIP 21                // 21*12 = 252 >= 246
#define NPLANE 96
#define NWAVE (NPLANE * NSTRIP)  // 2016
#define NBLOCK (NWAVE / 4)       // 504
#define OUTD 246
#define BUFW 272                 // 256 + 16 pad cols (zeroed)
#define C1V 1e-4f
#define C2V 9e-4f

__device__ __forceinline__ void load_pool(const float* __restrict__ xp,
                                          const float* __restrict__ yp,
                                          int r0, int i, int lane,
                                          float (&px)[4], float (&py)[4]) {
    int pr = r0 + i; pr = pr > 255 ? 255 : pr;   // clamp; clamped rows feed masked outputs only
    const float* xr = xp + (size_t)(2 * pr) * 512 + 8 * lane;
    const float* yr = yp + (size_t)(2 * pr) * 512 + 8 * lane;
    float4 a0 = *(const float4*)xr;
    float4 a1 = *(const float4*)(xr + 4);
    float4 b0 = *(const float4*)(xr + 512);
    float4 b1 = *(const float4*)(xr + 516);
    float4 c0 = *(const float4*)yr;
    float4 c1 = *(const float4*)(yr + 4);
    float4 d0 = *(const float4*)(yr + 512);
    float4 d1 = *(const float4*)(yr + 516);
    px[0] = (a0.x + a0.y + b0.x + b0.y) * 0.25f;
    px[1] = (a0.z + a0.w + b0.z + b0.w) * 0.25f;
    px[2] = (a1.x + a1.y + b1.x + b1.y) * 0.25f;
    px[3] = (a1.z + a1.w + b1.z + b1.w) * 0.25f;
    py[0] = (c0.x + c0.y + d0.x + d0.y) * 0.25f;
    py[1] = (c0.z + c0.w + d0.z + d0.w) * 0.25f;
    py[2] = (c1.x + c1.y + d1.x + d1.y) * 0.25f;
    py[3] = (c1.z + c1.w + d1.z + d1.w) * 0.25f;
}

__device__ __forceinline__ void step_row(float* vb, const float (&wt)[KS],
                                         float (&rx)[KS][4], float (&ry)[KS][4],
                                         const float (&px)[4], const float (&py)[4],
                                         int lane, int ro, float& local) {
    // push newest row into slot KS-1
    #pragma unroll
    for (int c = 0; c < 4; ++c) { rx[KS - 1][c] = px[c]; ry[KS - 1][c] = py[c]; }

    // vertical 11-tap, products on the fly (all register, static idx)
    float vmx[4] = {0,0,0,0}, vmy[4] = {0,0,0,0};
    float vxx[4] = {0,0,0,0}, vyy[4] = {0,0,0,0}, vxy[4] = {0,0,0,0};
    #pragma unroll
    for (int k = 0; k < KS; ++k) {
        float wk = wt[k];
        #pragma unroll
        for (int c = 0; c < 4; ++c) {
            float xv = rx[k][c], yv = ry[k][c];
            vmx[c] += wk * xv;       vmy[c] += wk * yv;
            vxx[c] += wk * xv * xv;  vyy[c] += wk * yv * yv;
            vxy[c] += wk * xv * yv;
        }
    }

    // stage 5 V-sum planes to wave-private LDS (b128, conflict-free)
    *(float4*)(vb + 0 * BUFW + 4 * lane) = make_float4(vmx[0], vmx[1], vmx[2], vmx[3]);
    *(float4*)(vb + 1 * BUFW + 4 * lane) = make_float4(vmy[0], vmy[1], vmy[2], vmy[3]);
    *(float4*)(vb + 2 * BUFW + 4 * lane) = make_float4(vxx[0], vxx[1], vxx[2], vxx[3]);
    *(float4*)(vb + 3 * BUFW + 4 * lane) = make_float4(vyy[0], vyy[1], vyy[2], vyy[3]);
    *(float4*)(vb + 4 * BUFW + 4 * lane) = make_float4(vxy[0], vxy[1], vxy[2], vxy[3]);
    __builtin_amdgcn_wave_barrier();   // pin order; in-wave DS ops execute in order

    // horizontal 11-tap: window cols 4l..4l+13 via 4 aligned b128 per plane
    float hp[5][4];
    #pragma unroll
    for (int p = 0; p < 5; ++p) {
        const float* bp = vb + p * BUFW + 4 * lane;
        float4 q0 = *(const float4*)bp;
        float4 q1 = *(const float4*)(bp + 4);
        float4 q2 = *(const float4*)(bp + 8);
        float4 q3 = *(const float4*)(bp + 12);
        float win[16] = {q0.x, q0.y, q0.z, q0.w, q1.x, q1.y, q1.z, q1.w,
                         q2.x, q2.y, q2.z, q2.w, q3.x, q3.y, q3.z, q3.w};
        #pragma unroll
        for (int c = 0; c < 4; ++c) {
            float a = 0.f;
            #pragma unroll
            for (int j = 0; j < KS; ++j) a += wt[j] * win[c + j];
            hp[p][c] = a;
        }
    }

    if (ro < OUTD) {
        #pragma unroll
        for (int c = 0; c < 4; ++c) {
            int oc = 4 * lane + c;
            float mx = hp[0][c], my = hp[1][c];
            float mxx = mx * mx, myy = my * my, mxy = mx * my;
            float sxx = hp[2][c] - mxx, syy = hp[3][c] - myy, sxy = hp[4][c] - mxy;
            float num = (2.f * mxy + C1V) * (2.f * sxy + C2V);
            float den = (mxx + myy + C1V) * (sxx + syy + C2V);
            float ss = num / den;
            local += (oc < OUTD) ? ss : 0.f;
        }
    }

    // rotate ring (static movs)
    #pragma unroll
    for (int k = 0; k < KS - 1; ++k) {
        #pragma unroll
        for (int c = 0; c < 4; ++c) { rx[k][c] = rx[k + 1][c]; ry[k][c] = ry[k + 1][c]; }
    }
}

__global__ __launch_bounds__(256) void ssim_wave(const float* __restrict__ x,
                                                 const float* __restrict__ y,
                                                 double* __restrict__ partial) {
    __shared__ float vbuf[4][5][BUFW];   // wave-private single buffer: 21.25 KB
    const int tid = threadIdx.x;
    const int wv = tid >> 6, lane = tid & 63;
    const int gid = blockIdx.x * 4 + wv;
    const int plane = gid / NSTRIP, strip = gid % NSTRIP;
    const int r0 = strip * H;
    const float* xp = x + (size_t)plane * (512 * 512);
    const float* yp = y + (size_t)plane * (512 * 512);

    float wt[KS];
    {
        float s = 0.f;
        #pragma unroll
        for (int i = 0; i < KS; ++i) {
            float d = (float)i - 5.f;
            wt[i] = expf(-d * d / 4.5f);   // 2*sigma^2 = 4.5
            s += wt[i];
        }
        float inv = 1.f / s;
        #pragma unroll
        for (int i = 0; i < KS; ++i) wt[i] *= inv;
    }

    // zero the 16 pad cols (reads beyond col 255 feed masked outputs)
    if (lane < BUFW - 256) {
        #pragma unroll
        for (int p = 0; p < 5; ++p)
            vbuf[wv][p][256 + lane] = 0.f;
    }
    __builtin_amdgcn_wave_barrier();

    // prime ring: rows 0..9 -> slots 0..9 (normal loads; TLP covers prologue)
    float rx[KS][4], ry[KS][4];
    #pragma unroll
    for (int i = 0; i < KS - 1; ++i)
        load_pool(xp, yp, r0, i, lane, rx[i], ry[i]);

    float cpx[4], cpy[4];
    load_pool(xp, yp, r0, KS - 1, lane, cpx, cpy);   // row 10 (first consumed row)

    float local = 0.f;
    float* vb = &vbuf[wv][0][0];

    // pipelined raw row: 8 x 16B opaque loads (x row-pair, y row-pair)
    f32x4 g0, g1, g2, g3, g4, g5, g6, g7;
    #define ISSUE_ROW(I)                                                            \
    {                                                                               \
        int pr_ = r0 + (I); pr_ = pr_ > 255 ? 255 : pr_;                            \
        const float* ax0_ = xp + (size_t)(2 * pr_) * 512 + 8 * lane;                \
        const float* ax1_ = ax0_ + 512;                                             \
        const float* ay0_ = yp + (size_t)(2 * pr_) * 512 + 8 * lane;                \
        const float* ay1_ = ay0_ + 512;                                             \
        asm volatile("global_load_dwordx4 %0, %1, off"           : "=v"(g0) : "v"(ax0_)); \
        asm volatile("global_load_dwordx4 %0, %1, off offset:16" : "=v"(g1) : "v"(ax0_)); \
        asm volatile("global_load_dwordx4 %0, %1, off"           : "=v"(g2) : "v"(ax1_)); \
        asm volatile("global_load_dwordx4 %0, %1, off offset:16" : "=v"(g3) : "v"(ax1_)); \
        asm volatile("global_load_dwordx4 %0, %1, off"           : "=v"(g4) : "v"(ay0_)); \
        asm volatile("global_load_dwordx4 %0, %1, off offset:16" : "=v"(g5) : "v"(ay0_)); \
        asm volatile("global_load_dwordx4 %0, %1, off"           : "=v"(g6) : "v"(ay1_)); \
        asm volatile("global_load_dwordx4 %0, %1, off offset:16" : "=v"(g7) : "v"(ay1_)); \
    }

    ISSUE_ROW(KS);   // row 11 in flight

    #pragma unroll 1
    for (int i = KS - 1; i < ROWS; ++i) {    // i = 10..21, 12 output rows
        step_row(vb, wt, rx, ry, cpx, cpy, lane, r0 + i - (KS - 1), local);

        // wait lands AFTER step_row; "+v" pass-through forces all consumers below
        asm volatile("s_waitcnt vmcnt(0)"
                     : "+v"(g0), "+v"(g1), "+v"(g2), "+v"(g3),
                       "+v"(g4), "+v"(g5), "+v"(g6), "+v"(g7));

        if (i < ROWS - 1) {                  // pool row i+1 for next iteration
            cpx[0] = (g0.x + g0.y + g2.x + g2.y) * 0.25f;
            cpx[1] = (g0.z + g0.w + g2.z + g2.w) * 0.25f;
            cpx[2] = (g1.x + g1.y + g3.x + g3.y) * 0.25f;
            cpx[3] = (g1.z + g1.w + g3.z + g3.w) * 0.25f;
            cpy[0] = (g4.x + g4.y + g6.x + g6.y) * 0.25f;
            cpy[1] = (g4.z + g4.w + g6.z + g6.w) * 0.25f;
            cpy[2] = (g5.x + g5.y + g7.x + g7.y) * 0.25f;
            cpy[3] = (g5.z + g5.w + g7.z + g7.w) * 0.25f;
        }
        if (i < ROWS - 2) ISSUE_ROW(i + 2);  // keep one row in flight
    }

    asm volatile("s_waitcnt vmcnt(0)");      // drain before reduce/store

    // wave reduce, one partial per wave
    #pragma unroll
    for (int off = 32; off > 0; off >>= 1)
        local += __shfl_down(local, off, 64);
    if (lane == 0) partial[gid] = (double)local;
}

__global__ __launch_bounds__(256) void ssim_finalize(const double* __restrict__ partial,
                                                     float* __restrict__ out) {
    const int tid = threadIdx.x;
    double s = 0.0;
    for (int i = tid; i < NWAVE; i += 256) s += partial[i];
    #pragma unroll
    for (int off = 32; off > 0; off >>= 1)
        s += __shfl_down(s, off, 64);
    __shared__ double sd[4];
    if ((tid & 63) == 0) sd[tid >> 6] = s;
    __syncthreads();
    if (tid == 0) {
        double total = sd[0] + sd[1] + sd[2] + sd[3];
        const double n = (double)NPLANE * OUTD * OUTD;   // 5,809,536
        out[0] = (float)(1.0 - total / n);
    }
}

extern "C" void kernel_launch(void* const* d_in, const int* in_sizes, int n_in,
                              void* d_out, int out_size, void* d_ws, size_t ws_size,
                              hipStream_t stream) {
    const float* x = (const float*)d_in[0];
    const float* y = (const float*)d_in[1];
    float* out = (float*)d_out;
    double* partial = (double*)d_ws;   // NWAVE * 8 = 15.75 KiB

    ssim_wave<<<NBLOCK, 256, 0, stream>>>(x, y, partial);
    ssim_finalize<<<1, 256, 0, stream>>>(partial, out);
}